// Round 1
// baseline (34.653 us; speedup 1.0000x reference)
//
#include <hip/hip_runtime.h>

#define N_ 8
#define C_ 64
#define L_ 512
#define D_ 64
#define TI 8          // rows per phase-2 block
#define JT 71         // staged band columns: TI-1 + 64
#define XR 72

#define C2F 2.8853900817779268f   // 2*log2(e)

__device__ __forceinline__ float rcp_f(float x) { return __builtin_amdgcn_rcpf(x); }

// ---------------- Phase 1: projections -------------------------------------
// Q2T[n][d][l] = (sum_c x[n][c][l]*Wt[c][d] + bh[d]) * C2F
// K2T[n][d][l] = (sum_c x[n][c][l]*Wx[c][d])          * C2F
__global__ __launch_bounds__(256) void proj_kernel(
    const float* __restrict__ x, const float* __restrict__ Wx,
    const float* __restrict__ Wt, const float* __restrict__ bh,
    float* __restrict__ Q2T, float* __restrict__ K2T)
{
  __shared__ float xs[C_][17];    // [c][l], 16-l tile, odd stride -> conflict-free
  __shared__ float wtl[C_][65];   // [c][d]
  __shared__ float wxl[C_][65];
  __shared__ float bhs[D_];
  const int tid = threadIdx.x;
  const int n  = blockIdx.x >> 5;
  const int l0 = (blockIdx.x & 31) << 4;

  for (int idx = tid; idx < C_ * 16; idx += 256) {
    int c = idx >> 4, l = idx & 15;
    xs[c][l] = x[(n * C_ + c) * L_ + l0 + l];
  }
  for (int idx = tid; idx < C_ * D_; idx += 256) {
    int c = idx >> 6, d = idx & 63;
    wtl[c][d] = Wt[idx];
    wxl[c][d] = Wx[idx];
  }
  if (tid < D_) bhs[tid] = bh[tid];
  __syncthreads();

  const int l  = tid & 15;
  const int db = tid >> 4;          // 0..15
  #pragma unroll
  for (int k = 0; k < 4; ++k) {
    const int d = db + 16 * k;
    float aq = 0.f, ak = 0.f;
    #pragma unroll 16
    for (int c = 0; c < C_; ++c) {
      float xv = xs[c][l];
      aq = fmaf(xv, wtl[c][d], aq);
      ak = fmaf(xv, wxl[c][d], ak);
    }
    Q2T[(n * D_ + d) * L_ + l0 + l] = (aq + bhs[d]) * C2F;
    K2T[(n * D_ + d) * L_ + l0 + l] = ak * C2F;
  }
}

// ---------------- Phase 2: banded scores + softmax + AV ---------------------
__global__ __launch_bounds__(256) void attn_kernel(
    const float* __restrict__ x, const float* __restrict__ Wa,
    const float* __restrict__ Q2T, const float* __restrict__ K2T,
    float* __restrict__ vout, float* __restrict__ aout)
{
  __shared__ float xT[XR][65];   // [jj][c], j = i0-32+jj
  __shared__ float k2b[D_][73];  // [d][jj]
  __shared__ float qs[D_][9];    // [d][il]
  __shared__ float ab[TI][64];   // [il][pos], a at j = i-32+pos
  __shared__ float vs[C_][9];    // [c][il]
  __shared__ float was[D_];

  const int tid  = threadIdx.x;
  const int lane = tid & 63;
  const int w    = tid >> 6;           // 0..3
  const int n    = blockIdx.x >> 6;
  const int i0   = (blockIdx.x & 63) << 3;
  const int jbase = i0 - 32;

  // stage x band tile (transposed), zero-fill out of range
  for (int idx = tid; idx < JT * C_; idx += 256) {
    int c = idx / JT, jj = idx % JT;
    int j = jbase + jj;
    xT[jj][c] = (j >= 0 && j < L_) ? x[(n * C_ + c) * L_ + j] : 0.f;
  }
  // stage K2 band
  const float* Kn = K2T + n * D_ * L_;
  for (int idx = tid; idx < JT * D_; idx += 256) {
    int d = idx / JT, jj = idx % JT;
    int j = jbase + jj;
    k2b[d][jj] = (j >= 0 && j < L_) ? Kn[d * L_ + j] : 0.f;
  }
  // stage Q2 tile
  const float* Qn = Q2T + n * D_ * L_;
  for (int idx = tid; idx < D_ * TI; idx += 256) {
    int d = idx >> 3, il = idx & 7;
    qs[d][il] = Qn[d * L_ + i0 + il];
  }
  if (tid < D_) was[tid] = Wa[tid];
  __syncthreads();

  // ---- scores: lane = band position, 2 rows per wave ----
  const int il0 = w * 2, il1 = w * 2 + 1;
  float acc0 = 0.f, acc1 = 0.f;
  #pragma unroll 4
  for (int dc = 0; dc < D_; ++dc) {
    float wa = was[dc];
    float q0 = qs[dc][il0];
    float q1 = qs[dc][il1];
    float k0 = k2b[dc][il0 + lane];
    float k1 = k2b[dc][il1 + lane];
    float t0 = exp2f(k0 + q0);          // e^{2x}
    float t1 = exp2f(k1 + q1);
    acc0 = fmaf(rcp_f(t0 + 1.f), wa, acc0);   // sigma(-2x) * Wa_d
    acc1 = fmaf(rcp_f(t1 + 1.f), wa, acc1);
  }

  float accs[2] = {acc0, acc1};
  #pragma unroll
  for (int ii = 0; ii < 2; ++ii) {
    const int il = w * 2 + ii;
    const int i  = i0 + il;
    const int j  = i - 32 + lane;                 // this lane's band column
    const bool valid = (j >= 0) && (j < L_);
    const float a = accs[ii];
    // band max of raw == band min of acc (raw = const - 2*acc)
    float m = valid ? a : 1e30f;
    #pragma unroll
    for (int off = 32; off; off >>= 1) m = fminf(m, __shfl_xor(m, off, 64));
    float p = valid ? exp2f(C2F * (m - a)) : 0.f;
    float s = p;
    #pragma unroll
    for (int off = 32; off; off >>= 1) s += __shfl_xor(s, off, 64);
    const float inv = rcp_f(s + 1e-6f);
    const float av = p * inv;
    ab[il][lane] = av;

    // coalesced a-row write: rotate so lane L holds the value for j === L (mod 64)
    const int src  = (lane - i + 32) & 63;
    const float ar = __shfl(av, src, 64);
    const int jsrc = i - 32 + src;                // === lane (mod 64)
    const int shit = (jsrc >= 0) ? (jsrc >> 6) : 99;
    float* arow = aout + (size_t)(n * L_ + i) * L_;
    #pragma unroll
    for (int s8 = 0; s8 < 8; ++s8)
      arow[s8 * 64 + lane] = (s8 == shit) ? ar : 0.f;
  }
  __syncthreads();

  // ---- v = a @ x^T (band only), lane = c ----
  #pragma unroll
  for (int ii = 0; ii < 2; ++ii) {
    const int il = w * 2 + ii;
    float v = 0.f;
    #pragma unroll 8
    for (int jj = 0; jj < 64; ++jj)
      v = fmaf(ab[il][jj], xT[il + jj][lane], v);
    vs[lane][il] = v;
  }
  __syncthreads();
  for (int idx = tid; idx < C_ * TI; idx += 256) {
    int c = idx >> 3, il = idx & 7;
    vout[(n * C_ + c) * L_ + i0 + il] = vs[c][il];
  }
}

extern "C" void kernel_launch(void* const* d_in, const int* in_sizes, int n_in,
                              void* d_out, int out_size, void* d_ws, size_t ws_size,
                              hipStream_t stream) {
  const float* x  = (const float*)d_in[0];
  const float* Wx = (const float*)d_in[1];   // key proj
  const float* Wt = (const float*)d_in[2];   // query proj
  const float* bh = (const float*)d_in[3];
  const float* Wa = (const float*)d_in[4];
  // d_in[5] (ba) cancels in the softmax: unused.

  float* vout = (float*)d_out;               // N*C*L
  float* aout = vout + N_ * C_ * L_;         // N*L*L
  float* Q2T  = (float*)d_ws;                // N*D*L
  float* K2T  = Q2T + N_ * D_ * L_;          // N*D*L  (2 MB total ws)

  proj_kernel<<<256, 256, 0, stream>>>(x, Wx, Wt, bh, Q2T, K2T);
  attn_kernel<<<512, 256, 0, stream>>>(x, Wa, Q2T, K2T, vout, aout);
}

// Round 2
// 30.350 us; speedup vs baseline: 1.1418x; 1.1418x over previous
//
#include <hip/hip_runtime.h>

#define N_ 8
#define C_ 64
#define L_ 512
#define D_ 64
#define TI 8          // rows per phase-2 block
#define JT 71         // staged band columns: TI-1 + 64
#define XR 72

#define C2F 2.8853900817779268f   // 2*log2(e)

__device__ __forceinline__ float rcp_f(float x) { return __builtin_amdgcn_rcpf(x); }
__device__ __forceinline__ float ex2(float x)   { return __builtin_amdgcn_exp2f(x); }

// ---------------- Phase 1: projections -------------------------------------
// Q2T[n][d][l] = (sum_c x[n][c][l]*Wt[c][d] + bh[d]) * C2F
// K2T[n][d][l] = (sum_c x[n][c][l]*Wx[c][d])          * C2F
// grid 512 (n, 8-l tile), 256 thr; W streamed from global (L1-resident 32KB).
__global__ __launch_bounds__(256) void proj_kernel(
    const float* __restrict__ x, const float* __restrict__ Wx,
    const float* __restrict__ Wt, const float* __restrict__ bh,
    float* __restrict__ Q2T, float* __restrict__ K2T)
{
  __shared__ float xs[C_][9];     // [c][l], 8-l tile
  __shared__ float bhs[D_];
  const int tid = threadIdx.x;
  const int n  = blockIdx.x >> 6;
  const int l0 = (blockIdx.x & 63) << 3;

  {
    int idx = tid;                 // 512 elements, 2 iters
    #pragma unroll
    for (int it = 0; it < 2; ++it, idx += 256) {
      int c = idx >> 3, l = idx & 7;
      xs[c][l] = x[(n * C_ + c) * L_ + l0 + l];
    }
  }
  if (tid < D_) bhs[tid] = bh[tid];
  __syncthreads();

  const int l  = tid & 7;
  const int dp = tid >> 3;         // 0..31  (d-pair)
  const float* wtp = Wt + 2 * dp;
  const float* wxp = Wx + 2 * dp;
  float q0 = 0.f, q1 = 0.f, k0 = 0.f, k1 = 0.f;
  #pragma unroll 8
  for (int c = 0; c < C_; ++c) {
    float2 wt = *(const float2*)(wtp + c * D_);
    float2 wx = *(const float2*)(wxp + c * D_);
    float xv = xs[c][l];
    q0 = fmaf(xv, wt.x, q0); q1 = fmaf(xv, wt.y, q1);
    k0 = fmaf(xv, wx.x, k0); k1 = fmaf(xv, wx.y, k1);
  }
  const int d0 = 2 * dp;
  float* qo = Q2T + (size_t)(n * D_ + d0) * L_ + l0 + l;
  float* ko = K2T + (size_t)(n * D_ + d0) * L_ + l0 + l;
  qo[0]  = (q0 + bhs[d0])     * C2F;
  qo[L_] = (q1 + bhs[d0 + 1]) * C2F;
  ko[0]  = k0 * C2F;
  ko[L_] = k1 * C2F;
}

// ---------------- Phase 2: banded scores + softmax + AV ---------------------
// grid 512 (n, 8-row tile), 512 thr = 8 waves, 1 row per wave.
__global__ __launch_bounds__(512) void attn_kernel(
    const float* __restrict__ x, const float* __restrict__ Wa,
    const float* __restrict__ Q2T, const float* __restrict__ K2T,
    float* __restrict__ vout, float* __restrict__ aout)
{
  __shared__ float xT[XR][65];   // [jj][c], j = i0-32+jj
  __shared__ float k2b[D_][73];  // [d][jj]
  __shared__ float qs[D_][9];    // [d][il]
  __shared__ float ab[TI][64];   // [il][pos]
  __shared__ float vs[C_][9];    // [c][il]
  __shared__ float was[D_];

  const int tid  = threadIdx.x;
  const int lane = tid & 63;
  const int w    = tid >> 6;            // 0..7, row within tile
  const int n    = blockIdx.x >> 6;
  const int i0   = (blockIdx.x & 63) << 3;
  const int jbase = i0 - 32;

  for (int idx = tid; idx < JT * C_; idx += 512) {
    int c = idx / JT, jj = idx % JT;
    int j = jbase + jj;
    xT[jj][c] = (j >= 0 && j < L_) ? x[(n * C_ + c) * L_ + j] : 0.f;
  }
  const float* Kn = K2T + (size_t)n * D_ * L_;
  for (int idx = tid; idx < JT * D_; idx += 512) {
    int d = idx / JT, jj = idx % JT;
    int j = jbase + jj;
    k2b[d][jj] = (j >= 0 && j < L_) ? Kn[d * L_ + j] : 0.f;
  }
  const float* Qn = Q2T + (size_t)n * D_ * L_;
  {
    int d = tid >> 3, il = tid & 7;
    qs[d][il] = Qn[d * L_ + i0 + il];
  }
  if (tid < D_) was[tid] = Wa[tid];
  __syncthreads();

  // ---- score row i0+w: lane = band position ----
  const int il = w;
  const int i  = i0 + il;
  float a0 = 0.f, a1 = 0.f, a2 = 0.f, a3 = 0.f;
  #pragma unroll
  for (int dc = 0; dc < D_; dc += 4) {
    float4 wv = *(const float4*)&was[dc];
    float q0v = qs[dc + 0][il], q1v = qs[dc + 1][il];
    float q2v = qs[dc + 2][il], q3v = qs[dc + 3][il];
    float k0 = k2b[dc + 0][il + lane];
    float k1 = k2b[dc + 1][il + lane];
    float k2 = k2b[dc + 2][il + lane];
    float k3 = k2b[dc + 3][il + lane];
    a0 = fmaf(rcp_f(ex2(k0 + q0v) + 1.f), wv.x, a0);   // sigma(-2x)*Wa_d
    a1 = fmaf(rcp_f(ex2(k1 + q1v) + 1.f), wv.y, a1);
    a2 = fmaf(rcp_f(ex2(k2 + q2v) + 1.f), wv.z, a2);
    a3 = fmaf(rcp_f(ex2(k3 + q3v) + 1.f), wv.w, a3);
  }
  const float acc = (a0 + a1) + (a2 + a3);

  // ---- softmax over band (raw = const - 2*acc -> band max == acc min) ----
  const int j = i - 32 + lane;
  const bool valid = (j >= 0) && (j < L_);
  float m = valid ? acc : 1e30f;
  #pragma unroll
  for (int off = 32; off; off >>= 1) m = fminf(m, __shfl_xor(m, off, 64));
  float p = valid ? ex2(C2F * (m - acc)) : 0.f;
  float s = p;
  #pragma unroll
  for (int off = 32; off; off >>= 1) s += __shfl_xor(s, off, 64);
  const float av = p * rcp_f(s + 1e-6f);
  ab[il][lane] = av;

  // coalesced a-row write: rotate so lane L holds value for column === L (mod 64)
  {
    const int src  = (lane - i + 32) & 63;
    const float ar = __shfl(av, src, 64);
    const int jsrc = i - 32 + src;            // === lane (mod 64)
    const int seg  = (jsrc >= 0) ? (jsrc >> 6) : 8;
    float* arow = aout + (size_t)(n * L_ + i) * L_;
    #pragma unroll
    for (int s8 = 0; s8 < 8; ++s8)
      arow[s8 * 64 + lane] = (s8 == seg) ? ar : 0.f;
  }

  // ---- v(row i) = sum_j a_ij * x[:,j], lane = c (ab written by own wave) ----
  {
    float v = 0.f;
    #pragma unroll
    for (int jj = 0; jj < 64; jj += 4) {
      float4 av4 = *(const float4*)&ab[il][jj];
      v = fmaf(av4.x, xT[il + jj + 0][lane], v);
      v = fmaf(av4.y, xT[il + jj + 1][lane], v);
      v = fmaf(av4.z, xT[il + jj + 2][lane], v);
      v = fmaf(av4.w, xT[il + jj + 3][lane], v);
    }
    vs[lane][il] = v;
  }
  __syncthreads();
  {
    int c = tid >> 3, il2 = tid & 7;
    vout[(size_t)(n * C_ + c) * L_ + i0 + il2] = vs[c][il2];
  }
}

extern "C" void kernel_launch(void* const* d_in, const int* in_sizes, int n_in,
                              void* d_out, int out_size, void* d_ws, size_t ws_size,
                              hipStream_t stream) {
  const float* x  = (const float*)d_in[0];
  const float* Wx = (const float*)d_in[1];   // key proj
  const float* Wt = (const float*)d_in[2];   // query proj
  const float* bh = (const float*)d_in[3];
  const float* Wa = (const float*)d_in[4];
  // d_in[5] (ba) cancels in the softmax: unused.

  float* vout = (float*)d_out;               // N*C*L
  float* aout = vout + N_ * C_ * L_;         // N*L*L
  float* Q2T  = (float*)d_ws;                // N*D*L
  float* K2T  = Q2T + N_ * D_ * L_;          // N*D*L  (2 MB total ws)

  proj_kernel<<<512, 256, 0, stream>>>(x, Wx, Wt, bh, Q2T, K2T);
  attn_kernel<<<512, 512, 0, stream>>>(x, Wa, Q2T, K2T, vout, aout);
}

// Round 3
// 24.958 us; speedup vs baseline: 1.3884x; 1.2160x over previous
//
#include <hip/hip_runtime.h>

#define N_ 8
#define C_ 64
#define L_ 512
#define D_ 64
#define TI 8          // rows per attn block
#define JT 71         // band cols per block: TI-1 + 64
#define KST 73        // k2b row stride (odd -> conflict-free col reads)
#define XST 65        // xT row stride

#define C2F 2.8853900817779268f   // 2*log2(e)

__device__ __forceinline__ float rcp_f(float x) { return __builtin_amdgcn_rcpf(x); }
__device__ __forceinline__ float ex2(float x)   { return __builtin_amdgcn_exp2f(x); }

// ---------------- Phase 1: projections, l-major outputs ---------------------
// Q2L[n][l][d] = (sum_c x[n][c][l]*Wt[c][d] + bh[d]) * C2F
// K2L[n][l][d] = (sum_c x[n][c][l]*Wx[c][d])          * C2F
// grid 512 = (n, 8-l tile); 256 thr = 32 d-pairs x 8 l.
__global__ __launch_bounds__(256) void proj_kernel(
    const float* __restrict__ x, const float* __restrict__ Wx,
    const float* __restrict__ Wt, const float* __restrict__ bh,
    float* __restrict__ Q2L, float* __restrict__ K2L)
{
  __shared__ float xs[C_][9];
  const int tid = threadIdx.x;
  const int n  = blockIdx.x >> 6;
  const int l0 = (blockIdx.x & 63) << 3;

  {
    int idx = tid;                 // 512 elements, 2 iters
    #pragma unroll
    for (int it = 0; it < 2; ++it, idx += 256) {
      int c = idx >> 3, l = idx & 7;
      xs[c][l] = x[(n * C_ + c) * L_ + l0 + l];
    }
  }
  __syncthreads();

  const int d2 = (tid & 31) << 1;   // d base (pair)
  const int l  = tid >> 5;          // 0..7
  const float* wtp = Wt + d2;
  const float* wxp = Wx + d2;
  float q0 = 0.f, q1 = 0.f, k0 = 0.f, k1 = 0.f;
  #pragma unroll 16
  for (int c = 0; c < C_; ++c) {
    float2 wt = *(const float2*)(wtp + c * D_);
    float2 wx = *(const float2*)(wxp + c * D_);
    float xv = xs[c][l];
    q0 = fmaf(xv, wt.x, q0); q1 = fmaf(xv, wt.y, q1);
    k0 = fmaf(xv, wx.x, k0); k1 = fmaf(xv, wx.y, k1);
  }
  float2 bv = *(const float2*)(bh + d2);
  const size_t row = ((size_t)n * L_ + l0 + l) * D_ + d2;
  float2 qo = { (q0 + bv.x) * C2F, (q1 + bv.y) * C2F };
  float2 ko = { k0 * C2F, k1 * C2F };
  *(float2*)(Q2L + row) = qo;
  *(float2*)(K2L + row) = ko;
}

// ---------------- Phase 2: banded scores + softmax + AV ---------------------
// grid 512 = (n, 8-row tile); 512 thr = 8 waves, 1 row per wave.
__global__ __launch_bounds__(512) void attn_kernel(
    const float* __restrict__ x, const float* __restrict__ Wa,
    const float* __restrict__ Q2L, const float* __restrict__ K2L,
    float* __restrict__ vout, float* __restrict__ aout)
{
  __shared__ float xT[JT][XST];    // [jj][c]
  __shared__ float k2b[D_][KST];   // [d][jj]
  __shared__ float ab[TI][64];     // [row][band pos], stride 64 (aligned b128 rows)
  __shared__ float vs[C_][9];      // [c][row]

  const int tid  = threadIdx.x;
  const int lane = tid & 63;
  const int n    = blockIdx.x >> 6;
  const int i0   = (blockIdx.x & 63) << 3;
  const int jbase = i0 - 32;

  // ---- stage xT[jj][c] from x[n][c][j]: float4 along l, b32 scatter ----
  for (int idx = tid; idx < C_ * 18; idx += 512) {
    int c = idx / 18, t = idx - c * 18;
    int jj = t << 2;
    int j = jbase + jj;                       // j % 4 == 0: chunk fully in or out
    float4 xv = {0.f, 0.f, 0.f, 0.f};
    if (j >= 0 && j < L_) xv = *(const float4*)(x + (n * C_ + c) * L_ + j);
    xT[jj + 0][c] = xv.x;
    xT[jj + 1][c] = xv.y;
    xT[jj + 2][c] = xv.z;
    if (jj + 3 < JT) xT[jj + 3][c] = xv.w;
  }
  // ---- stage k2b[d][jj] from K2L[n][j][d]: coalesced float4, b32 scatter ----
  for (int idx = tid; idx < JT * 16; idx += 512) {
    int jj = idx >> 4, d4 = (idx & 15) << 2;
    int j = jbase + jj;
    float4 kv = {0.f, 0.f, 0.f, 0.f};
    if (j >= 0 && j < L_) kv = *(const float4*)(K2L + ((size_t)n * L_ + j) * D_ + d4);
    k2b[d4 + 0][jj] = kv.x;
    k2b[d4 + 1][jj] = kv.y;
    k2b[d4 + 2][jj] = kv.z;
    k2b[d4 + 3][jj] = kv.w;
  }
  __syncthreads();

  // ---- score row i = i0 + wu: lane = band position ----
  const int wu = __builtin_amdgcn_readfirstlane(tid >> 6);  // uniform row-in-tile
  const int i  = i0 + wu;
  const float* qrow = Q2L + ((size_t)n * L_ + i) * D_;      // uniform -> s_load
  const float* kcol = &k2b[0][0] + wu + lane;               // + d*KST per d
  float a0 = 0.f, a1 = 0.f, a2 = 0.f, a3 = 0.f;
  #pragma unroll
  for (int dc = 0; dc < D_; dc += 4) {
    float k0 = kcol[(dc + 0) * KST];
    float k1 = kcol[(dc + 1) * KST];
    float k2v = kcol[(dc + 2) * KST];
    float k3 = kcol[(dc + 3) * KST];
    float q0 = qrow[dc + 0], q1 = qrow[dc + 1];
    float q2v = qrow[dc + 2], q3 = qrow[dc + 3];
    float w0 = Wa[dc + 0], w1 = Wa[dc + 1];
    float w2v = Wa[dc + 2], w3 = Wa[dc + 3];
    a0 = fmaf(rcp_f(ex2(k0 + q0) + 1.f), w0, a0);   // sigma(-2x)*Wa_d
    a1 = fmaf(rcp_f(ex2(k1 + q1) + 1.f), w1, a1);
    a2 = fmaf(rcp_f(ex2(k2v + q2v) + 1.f), w2v, a2);
    a3 = fmaf(rcp_f(ex2(k3 + q3) + 1.f), w3, a3);
  }
  const float acc = (a0 + a1) + (a2 + a3);

  // ---- band softmax (raw = const - 2*acc -> band max == acc min) ----
  const int j = i - 32 + lane;
  const bool valid = (j >= 0) && (j < L_);
  float m = valid ? acc : 1e30f;
  #pragma unroll
  for (int off = 32; off; off >>= 1) m = fminf(m, __shfl_xor(m, off, 64));
  float p = valid ? ex2(C2F * (m - acc)) : 0.f;
  float s = p;
  #pragma unroll
  for (int off = 32; off; off >>= 1) s += __shfl_xor(s, off, 64);
  const float av = p * rcp_f(s + 1e-6f);
  ab[wu][lane] = av;

  // coalesced a-row write: rotate so lane L holds value for column === L (mod 64)
  {
    const int src  = (lane - i + 32) & 63;
    const float ar = __shfl(av, src, 64);
    const int jsrc = i - 32 + src;            // === lane (mod 64)
    const int seg  = (jsrc >= 0) ? (jsrc >> 6) : 9;   // >=8 when out of range
    float* arow = aout + (size_t)(n * L_ + i) * L_;
    #pragma unroll
    for (int s8 = 0; s8 < 8; ++s8)
      arow[s8 * 64 + lane] = (s8 == seg) ? ar : 0.f;
  }

  // ---- v(row i) = sum_p a_p * x[:, i-32+p], lane = c ----
  {
    float v = 0.f;
    const float* xp = &xT[wu][0] + lane;              // + p*XST per band pos
    const float4* ap = (const float4*)&ab[wu][0];     // aligned uniform b128
    #pragma unroll
    for (int t = 0; t < 16; ++t) {
      float4 a4 = ap[t];
      v = fmaf(a4.x, xp[(4 * t + 0) * XST], v);
      v = fmaf(a4.y, xp[(4 * t + 1) * XST], v);
      v = fmaf(a4.z, xp[(4 * t + 2) * XST], v);
      v = fmaf(a4.w, xp[(4 * t + 3) * XST], v);
    }
    vs[lane][wu] = v;
  }
  __syncthreads();
  {
    int c = tid >> 3, il = tid & 7;
    vout[((size_t)n * C_ + c) * L_ + i0 + il] = vs[c][il];
  }
}

extern "C" void kernel_launch(void* const* d_in, const int* in_sizes, int n_in,
                              void* d_out, int out_size, void* d_ws, size_t ws_size,
                              hipStream_t stream) {
  const float* x  = (const float*)d_in[0];
  const float* Wx = (const float*)d_in[1];   // key proj
  const float* Wt = (const float*)d_in[2];   // query proj
  const float* bh = (const float*)d_in[3];
  const float* Wa = (const float*)d_in[4];
  // d_in[5] (ba) cancels in the softmax: unused.

  float* vout = (float*)d_out;               // N*C*L
  float* aout = vout + N_ * C_ * L_;         // N*L*L
  float* Q2L  = (float*)d_ws;                // N*L*D (l-major)
  float* K2L  = Q2L + N_ * L_ * D_;          // N*L*D

  proj_kernel<<<512, 256, 0, stream>>>(x, Wx, Wt, bh, Q2L, K2L);
  attn_kernel<<<512, 512, 0, stream>>>(x, Wa, Q2L, K2L, vout, aout);
}

// Round 4
// 24.436 us; speedup vs baseline: 1.4181x; 1.0214x over previous
//
#include <hip/hip_runtime.h>

#define N_ 8
#define C_ 64
#define L_ 512
#define D_ 64
#define TI 8          // rows per attn block
#define JT 71         // band cols per block: TI-1 + 64
#define KST 68        // k2b[jj][d] stride (dwords): mult of 4, ==4 mod 32 -> balanced b128
#define XST 76        // xs[c][jj] stride: mult of 4, ==12 mod 32 -> balanced b128
#define AST 76        // ash row stride

#define C2F 2.8853900817779268f   // 2*log2(e)

__device__ __forceinline__ float rcp_f(float x) { return __builtin_amdgcn_rcpf(x); }
__device__ __forceinline__ float ex2(float x)   { return __builtin_amdgcn_exp2f(x); }

// ---------------- Phase 1: projections, l-major outputs ---------------------
// Q2L[n][l][d] = (sum_c x[n][c][l]*Wt[c][d] + bh[d]) * C2F
// K2L[n][l][d] = (sum_c x[n][c][l]*Wx[c][d])          * C2F
__global__ __launch_bounds__(256) void proj_kernel(
    const float* __restrict__ x, const float* __restrict__ Wx,
    const float* __restrict__ Wt, const float* __restrict__ bh,
    float* __restrict__ Q2L, float* __restrict__ K2L)
{
  __shared__ float xs[C_][9];
  const int tid = threadIdx.x;
  const int n  = blockIdx.x >> 6;
  const int l0 = (blockIdx.x & 63) << 3;

  {
    int idx = tid;
    #pragma unroll
    for (int it = 0; it < 2; ++it, idx += 256) {
      int c = idx >> 3, l = idx & 7;
      xs[c][l] = x[(n * C_ + c) * L_ + l0 + l];
    }
  }
  __syncthreads();

  const int d2 = (tid & 31) << 1;
  const int l  = tid >> 5;
  const float* wtp = Wt + d2;
  const float* wxp = Wx + d2;
  float q0 = 0.f, q1 = 0.f, k0 = 0.f, k1 = 0.f;
  #pragma unroll 16
  for (int c = 0; c < C_; ++c) {
    float2 wt = *(const float2*)(wtp + c * D_);
    float2 wx = *(const float2*)(wxp + c * D_);
    float xv = xs[c][l];
    q0 = fmaf(xv, wt.x, q0); q1 = fmaf(xv, wt.y, q1);
    k0 = fmaf(xv, wx.x, k0); k1 = fmaf(xv, wx.y, k1);
  }
  float2 bv = *(const float2*)(bh + d2);
  const size_t row = ((size_t)n * L_ + l0 + l) * D_ + d2;
  float2 qo = { (q0 + bv.x) * C2F, (q1 + bv.y) * C2F };
  float2 ko = { k0 * C2F, k1 * C2F };
  *(float2*)(Q2L + row) = qo;
  *(float2*)(K2L + row) = ko;
}

// ---------------- Phase 2: banded scores + softmax + AV ---------------------
// grid 512 = (n, 8-row tile); 512 thr = 8 waves, 1 row per wave.
__global__ __launch_bounds__(512) void attn_kernel(
    const float* __restrict__ x, const float* __restrict__ Wa,
    const float* __restrict__ Q2L, const float* __restrict__ K2L,
    float* __restrict__ vout, float* __restrict__ aout)
{
  __shared__ float xs[C_ * XST];    // [c][jj]
  __shared__ float k2b[JT * KST];   // [jj][d]
  __shared__ float ash[TI * AST];   // [row][jj]: a at band col jj, zero-padded
  __shared__ float vs[C_][9];       // [c][row]

  const int tid  = threadIdx.x;
  const int lane = tid & 63;
  const int n    = blockIdx.x >> 6;
  const int i0   = (blockIdx.x & 63) << 3;
  const int jbase = i0 - 32;

  // ---- stage xs[c][jj]: 1 float4 global -> 1 ds_write_b128 ----
  for (int idx = tid; idx < C_ * 18; idx += 512) {
    int c = idx / 18, qq = idx - c * 18;
    int jj = qq << 2;
    int j = jbase + jj;                      // j % 4 == 0: quad fully in or out
    float4 xv = {0.f, 0.f, 0.f, 0.f};
    if (j >= 0 && j < L_) xv = *(const float4*)(x + (n * C_ + c) * L_ + j);
    *(float4*)&xs[c * XST + jj] = xv;
  }
  // ---- stage k2b[jj][d]: 1 float4 global -> 1 ds_write_b128 ----
  for (int idx = tid; idx < JT * 16; idx += 512) {
    int jj = idx >> 4, d4 = (idx & 15) << 2;
    int j = jbase + jj;
    float4 kv = {0.f, 0.f, 0.f, 0.f};
    if (j >= 0 && j < L_) kv = *(const float4*)(K2L + ((size_t)n * L_ + j) * D_ + d4);
    *(float4*)&k2b[jj * KST + d4] = kv;
  }
  __syncthreads();

  // ---- score row i = i0 + wu: lane = band position, b128 k-reads ----
  const int wu = __builtin_amdgcn_readfirstlane(tid >> 6);
  const int i  = i0 + wu;
  const float* qrow = Q2L + ((size_t)n * L_ + i) * D_;   // uniform -> s_load
  const float* kp = &k2b[(wu + lane) * KST];
  float a0 = 0.f, a1 = 0.f, a2 = 0.f, a3 = 0.f;
  #pragma unroll
  for (int dc = 0; dc < D_; dc += 4) {
    float4 kv = *(const float4*)(kp + dc);
    float4 qv = *(const float4*)(qrow + dc);
    float4 wv = *(const float4*)(Wa + dc);
    a0 = fmaf(rcp_f(ex2(kv.x + qv.x) + 1.f), wv.x, a0);   // sigma(-2x)*Wa_d
    a1 = fmaf(rcp_f(ex2(kv.y + qv.y) + 1.f), wv.y, a1);
    a2 = fmaf(rcp_f(ex2(kv.z + qv.z) + 1.f), wv.z, a2);
    a3 = fmaf(rcp_f(ex2(kv.w + qv.w) + 1.f), wv.w, a3);
  }
  const float acc = (a0 + a1) + (a2 + a3);

  // ---- band softmax (raw = const - 2*acc -> band max == acc min) ----
  const int j = i - 32 + lane;
  const bool valid = (j >= 0) && (j < L_);
  float m = valid ? acc : 1e30f;
  #pragma unroll
  for (int off = 32; off; off >>= 1) m = fminf(m, __shfl_xor(m, off, 64));
  float p = valid ? ex2(C2F * (m - acc)) : 0.f;
  float s = p;
  #pragma unroll
  for (int off = 32; off; off >>= 1) s += __shfl_xor(s, off, 64);
  const float av = p * rcp_f(s + 1e-6f);

  // shifted a row: ash[wu][jj] = a[jj - wu], zero elsewhere (same-wave use only)
  float* arow_s = &ash[wu * AST];
  arow_s[lane] = 0.f;
  if (lane < AST - 64) arow_s[64 + lane] = 0.f;
  arow_s[wu + lane] = av;

  // coalesced a-row global write: rotate so lane L holds value for col === L (mod 64)
  {
    const int src  = (lane - i + 32) & 63;
    const float ar = __shfl(av, src, 64);
    const int jsrc = i - 32 + src;            // === lane (mod 64)
    const int seg  = (jsrc >= 0) ? (jsrc >> 6) : 9;
    float* arow = aout + (size_t)(n * L_ + i) * L_;
    #pragma unroll
    for (int s8 = 0; s8 < 8; ++s8)
      arow[s8 * 64 + lane] = (s8 == seg) ? ar : 0.f;
  }

  // ---- v(row i) = sum_jj ash[jj] * xs[c][jj], lane = c, all-b128 ----
  {
    const int qstart = wu & ~3;               // quad window [qstart, qstart+68)
    float v = 0.f;
    const float* xp = &xs[lane * XST];
    #pragma unroll
    for (int t = 0; t < 17; ++t) {
      const int jj = qstart + 4 * t;
      float4 a4 = *(const float4*)(arow_s + jj);   // uniform broadcast
      float4 xq = *(const float4*)(xp + jj);       // balanced strided b128
      v = fmaf(a4.x, xq.x, v);
      v = fmaf(a4.y, xq.y, v);
      v = fmaf(a4.z, xq.z, v);
      v = fmaf(a4.w, xq.w, v);
    }
    vs[lane][wu] = v;
  }
  __syncthreads();
  {
    int c = tid >> 3, il = tid & 7;
    vout[((size_t)n * C_ + c) * L_ + i0 + il] = vs[c][il];
  }
}

extern "C" void kernel_launch(void* const* d_in, const int* in_sizes, int n_in,
                              void* d_out, int out_size, void* d_ws, size_t ws_size,
                              hipStream_t stream) {
  const float* x  = (const float*)d_in[0];
  const float* Wx = (const float*)d_in[1];   // key proj
  const float* Wt = (const float*)d_in[2];   // query proj
  const float* bh = (const float*)d_in[3];
  const float* Wa = (const float*)d_in[4];
  // d_in[5] (ba) cancels in the softmax: unused.

  float* vout = (float*)d_out;               // N*C*L
  float* aout = vout + N_ * C_ * L_;         // N*L*L
  float* Q2L  = (float*)d_ws;                // N*L*D (l-major)
  float* K2L  = Q2L + N_ * L_ * D_;          // N*L*D

  proj_kernel<<<512, 256, 0, stream>>>(x, Wx, Wt, bh, Q2L, K2L);
  attn_kernel<<<512, 512, 0, stream>>>(x, Wa, Q2L, K2L, vout, aout);
}